// Round 8
// baseline (715.929 us; speedup 1.0000x reference)
//
#include <hip/hip_runtime.h>
#include <hip/hip_bf16.h>

// EdgeConv, CSR-by-dst, bf16 intermediates:
//   abf[n] = bf16(h@W1[0:64]); bsf[n] = bf16(h@W1[64:128]+b1)
//   acc[n] = sum_{e:dst=n} relu(abf[src] + bsf[n] + e*w128)   (wave/node, lane=feat)
//   out[n] = acc[n] @ W2 + cnt[n]*b2                          (fused readlane matvec)
// R8: node_accum = R3 exactly (proven 88.5us; epilogue alternatives lost 3x:
//   VGPR hoist sunk by regalloc (R4/R6), LDS ds_read_b32 throughput 5.8cyc <
//   L1-hot VMEM (R7)). precompute: LDS staging DELETED — it was LDS-bound
//   (16 wave-uniform ds_read_b128/node @12cyc = 31us of LDS issue for 16B each);
//   h rows now read with wave-uniform global_load_dwordx4 (opaque-VGPR z forces
//   vector path, L1 broadcasts; ~4cyc issue, overlapped under 128 fma/node).
//   Shard machinery deleted (vestigial since rank-based fill): alloc uses one
//   global cursor; shard_sum kernel gone (5 kernels total).

#define PRE_NPW 32    // precompute: nodes per wave (block of 4 waves covers 128)

typedef unsigned int u32;

// ---------------- count + rank ----------------
__global__ void count_kernel(const int* __restrict__ dst, int* __restrict__ counts,
                             int* __restrict__ rank, int n_edges) {
    int i = blockIdx.x * blockDim.x + threadIdx.x;
    if (i < n_edges) rank[i] = atomicAdd(&counts[dst[i]], 1);
}

// ---------------- offset allocation, single global cursor ----------------
// block: wave-scan of counts -> block sum -> base = atomicAdd(gcursor, sum).
// Segments are disjoint and sized exactly; base order is execution order
// (irrelevant: node_accum only needs offs[n] + rank-ordered contents).
__global__ __launch_bounds__(256) void alloc_offs_kernel(const int* __restrict__ counts,
                                                         int* __restrict__ gcursor,
                                                         int* __restrict__ offs, int n) {
    __shared__ int wsum[4];
    const int i    = blockIdx.x * 256 + threadIdx.x;
    const int lane = threadIdx.x & 63;
    const int wv   = threadIdx.x >> 6;

    const int c = (i < n) ? counts[i] : 0;
    int incl = c;
    #pragma unroll
    for (int d = 1; d < 64; d <<= 1) {
        int v = __shfl_up(incl, d, 64);
        if (lane >= d) incl += v;
    }
    const int excl = incl - c;
    if (lane == 63) wsum[wv] = incl;
    __syncthreads();
    if (threadIdx.x == 0) {
        const int s0 = wsum[0], s1 = wsum[1], s2 = wsum[2], s3 = wsum[3];
        const int b = atomicAdd(gcursor, s0 + s1 + s2 + s3);
        wsum[0] = b; wsum[1] = b + s0; wsum[2] = b + s0 + s1; wsum[3] = b + s0 + s1 + s2;
    }
    __syncthreads();
    if (i < n) offs[i] = wsum[wv] + excl;
}

// ---------------- single-pass non-atomic fill ----------------
__global__ void fill_kernel(const int* __restrict__ dst, const int* __restrict__ src,
                            const float* __restrict__ e,
                            const int* __restrict__ offs, const int* __restrict__ rank,
                            int2* __restrict__ meta, int n_edges) {
    const int i = blockIdx.x * blockDim.x + threadIdx.x;
    if (i >= n_edges) return;
    const int d = dst[i];
    meta[offs[d] + rank[i]] = make_int2(src[i], __float_as_int(e[i]));
}

// ---------------- abf = bf16(h@W1t), bsf = bf16(h@W1b + b1) ----------------
// lane = output feature j; wreg[k] = W1[k][j] pinned in 128 VGPRs.
// h rows: wave-uniform global_load_dwordx4 (opaque z forces vector path; L1
// broadcast, ~4cyc issue) — no LDS, no barriers, no staging machinery.
__global__ __launch_bounds__(256, 2) void precompute_ab_kernel(
    const float* __restrict__ h, const float* __restrict__ W1, const float* __restrict__ b1,
    unsigned short* __restrict__ abf, unsigned short* __restrict__ bsf, int n_nodes)
{
    const int lane = threadIdx.x & 63;
    const int wv   = threadIdx.x >> 6;
    const int n0   = (blockIdx.x * 4 + wv) * PRE_NPW;   // wave's first node
    if (n0 >= n_nodes) return;

    // opaque VGPR zero: taints addresses -> compiler must use vector loads
    // (R1 failure mode was SGPR-starved s_load streaming of the row operand)
    int z;
    asm volatile("v_mov_b32 %0, 0" : "=v"(z));

    // whole W1 column for this lane in VGPRs, loaded once per wave (L2-hot);
    // volatile asm pin: non-sinkable -> allocator can't push loads into the loop
    float wreg[128];
    #pragma unroll
    for (int k = 0; k < 128; ++k) wreg[k] = W1[(size_t)k * 64 + lane];
    #pragma unroll
    for (int k = 0; k < 128; ++k) asm volatile("" : "+v"(wreg[k]));
    const float b1l = b1[lane];

    for (int t = 0; t < PRE_NPW; ++t) {
        const int n = n0 + t;
        if (n >= n_nodes) break;

        const float4* hr = reinterpret_cast<const float4*>(h + (size_t)n * 64 + z);
        float4 h4[16];
        #pragma unroll
        for (int k4 = 0; k4 < 16; ++k4) h4[k4] = hr[k4];   // 16x uniform dwordx4, pipelined

        float av = 0.f, bv = b1l;
        #pragma unroll
        for (int k4 = 0; k4 < 16; ++k4) {    // same fma order as R3/R5 (bitwise id.)
            av = fmaf(h4[k4].x, wreg[4 * k4 + 0], av);
            bv = fmaf(h4[k4].x, wreg[64 + 4 * k4 + 0], bv);
            av = fmaf(h4[k4].y, wreg[4 * k4 + 1], av);
            bv = fmaf(h4[k4].y, wreg[64 + 4 * k4 + 1], bv);
            av = fmaf(h4[k4].z, wreg[4 * k4 + 2], av);
            bv = fmaf(h4[k4].z, wreg[64 + 4 * k4 + 2], bv);
            av = fmaf(h4[k4].w, wreg[4 * k4 + 3], av);
            bv = fmaf(h4[k4].w, wreg[64 + 4 * k4 + 3], bv);
        }
        __hip_bfloat16 ab = __float2bfloat16(av);
        __hip_bfloat16 bb = __float2bfloat16(bv);
        abf[(size_t)n * 64 + lane] = *reinterpret_cast<unsigned short*>(&ab);
        bsf[(size_t)n * 64 + lane] = *reinterpret_cast<unsigned short*>(&bb);
    }
}

// ---------------- accum: wave/node, lane=feat, register-meta + depth-8 prefetch ----------------
// (R3 exactly — proven 88.5us twice; epilogue W2 via L1-hot VMEM is the local floor)
__global__ __launch_bounds__(256) void node_accum_kernel(
    const unsigned short* __restrict__ abf, const unsigned short* __restrict__ bsf,
    const float* __restrict__ W1, const float* __restrict__ W2, const float* __restrict__ b2,
    const int* __restrict__ offs, const int* __restrict__ counts,
    const int2* __restrict__ meta, float* __restrict__ out, int n_nodes)
{
    const int lane = threadIdx.x & 63;
    const int wv   = __builtin_amdgcn_readfirstlane(threadIdx.x >> 6);
    const int n    = blockIdx.x * 4 + wv;          // wave-uniform node id
    if (n >= n_nodes) return;

    const float basel = __uint_as_float((uint)bsf[(size_t)n * 64 + lane] << 16);
    const float w128l = W1[(size_t)128 * 64 + lane];
    float acc = 0.f;

    const int beg = offs[n];     // s_load (n uniform)
    const int np  = counts[n];   // s_load

    // chunks of <=64 edges: meta staged into registers by ONE lane-parallel load,
    // per-edge src/e extracted with v_readlane (no memory on the gather-addr path)
    for (int c0 = 0; c0 < np; c0 += 64) {
        const int cn = min(np - c0, 64);

        int mx = 0, my = 0;
        if (lane < cn) {
            const int2 m = meta[beg + c0 + lane];   // 512B coalesced, once per chunk
            mx = m.x; my = m.y;
        }

        // pipeline slots hold the RAW zext ushort; <<16 happens at consume time
        uint x0=0,x1=0,x2=0,x3=0,x4=0,x5=0,x6=0,x7=0;

        auto ld = [&](int j, uint& x) {
            const int s = __builtin_amdgcn_readlane(mx, j);        // uniform src id
            x = (uint)abf[(size_t)s * 64 + lane];                  // saddr gather, 128B/wave
        };
        auto step = [&](int j, uint xr) {
            const float ev = __uint_as_float((uint)__builtin_amdgcn_readlane(my, j));
            const float xv = __uint_as_float(xr << 16);
            acc += fmaxf(fmaf(ev, w128l, basel) + xv, 0.f);
        };

        if (cn > 0) ld(0, x0);
        if (cn > 1) ld(1, x1);
        if (cn > 2) ld(2, x2);
        if (cn > 3) ld(3, x3);
        if (cn > 4) ld(4, x4);
        if (cn > 5) ld(5, x5);
        if (cn > 6) ld(6, x6);
        if (cn > 7) ld(7, x7);

        int i = 0;
        while (i + 16 <= cn) {
            step(i + 0, x0); ld(i + 8,  x0);
            step(i + 1, x1); ld(i + 9,  x1);
            step(i + 2, x2); ld(i + 10, x2);
            step(i + 3, x3); ld(i + 11, x3);
            step(i + 4, x4); ld(i + 12, x4);
            step(i + 5, x5); ld(i + 13, x5);
            step(i + 6, x6); ld(i + 14, x6);
            step(i + 7, x7); ld(i + 15, x7);
            i += 8;
        }
        const int r = cn - i;   // 0..15
        if (r > 0)  { step(i + 0, x0); }  if (r > 8)  { ld(i + 8,  x0); }
        if (r > 1)  { step(i + 1, x1); }  if (r > 9)  { ld(i + 9,  x1); }
        if (r > 2)  { step(i + 2, x2); }  if (r > 10) { ld(i + 10, x2); }
        if (r > 3)  { step(i + 3, x3); }  if (r > 11) { ld(i + 11, x3); }
        if (r > 4)  { step(i + 4, x4); }  if (r > 12) { ld(i + 12, x4); }
        if (r > 5)  { step(i + 5, x5); }  if (r > 13) { ld(i + 13, x5); }
        if (r > 6)  { step(i + 6, x6); }  if (r > 14) { ld(i + 14, x6); }
        if (r > 7)  { step(i + 7, x7); }
        if (r > 8)  { step(i + 8,  x0); }
        if (r > 9)  { step(i + 9,  x1); }
        if (r > 10) { step(i + 10, x2); }
        if (r > 11) { step(i + 11, x3); }
        if (r > 12) { step(i + 12, x4); }
        if (r > 13) { step(i + 13, x5); }
        if (r > 14) { step(i + 14, x6); }
    }

    // fused epilogue: out[n][lane] = sum_j acc_j * W2[j][lane] + np*b2[lane]
    float o = (float)np * b2[lane];
    #pragma unroll
    for (int j = 0; j < 64; ++j) {
        const float aj = __shfl(acc, j, 64);               // v_readlane
        o = fmaf(aj, W2[(size_t)j * 64 + lane], o);        // coalesced, L1-hot
    }
    out[(size_t)n * 64 + lane] = o;
}

extern "C" void kernel_launch(void* const* d_in, const int* in_sizes, int n_in,
                              void* d_out, int out_size, void* d_ws, size_t ws_size,
                              hipStream_t stream) {
    const float* h  = (const float*)d_in[0];
    const float* e  = (const float*)d_in[1];
    const int* src  = (const int*)d_in[2];
    const int* dst  = (const int*)d_in[3];
    const float* W1 = (const float*)d_in[4];
    const float* b1 = (const float*)d_in[5];
    const float* W2 = (const float*)d_in[6];
    const float* b2 = (const float*)d_in[7];
    float* out = (float*)d_out;

    const int n_edges = in_sizes[2];
    const int N = in_sizes[0] / 64;

    // ws: [counts N | gcursor 8 (1 used) | offs N | rank E] ints,
    //     [meta 2E] ints, [abf 64N ushort], [bsf 64N ushort]
    int* counts  = (int*)d_ws;
    int* gcursor = counts + N;
    int* offs    = gcursor + 8;
    int* rank    = offs + N;
    int2* meta   = (int2*)(rank + n_edges);
    unsigned short* abf = (unsigned short*)(meta + n_edges);
    unsigned short* bsf = abf + (size_t)64 * N;

    // zero counts + cursor every call
    hipMemsetAsync(counts, 0, ((size_t)N + 8) * sizeof(int), stream);

    const int eb = (n_edges + 255) / 256;
    const int nb = (N + 255) / 256;
    const int pg = (N + 4 * PRE_NPW - 1) / (4 * PRE_NPW);

    precompute_ab_kernel<<<pg, 256, 0, stream>>>(h, W1, b1, abf, bsf, N);
    count_kernel<<<eb, 256, 0, stream>>>(dst, counts, rank, n_edges);
    alloc_offs_kernel<<<nb, 256, 0, stream>>>(counts, gcursor, offs, N);
    fill_kernel<<<eb, 256, 0, stream>>>(dst, src, e, offs, rank, meta, n_edges);
    node_accum_kernel<<<(N + 3) / 4, 256, 0, stream>>>(abf, bsf, W1, W2, b2,
                                                       offs, counts, meta, out, N);
}

// Round 9
// 222.372 us; speedup vs baseline: 3.2195x; 3.2195x over previous
//
#include <hip/hip_runtime.h>
#include <hip/hip_bf16.h>

// EdgeConv, CSR-by-dst, bf16 intermediates:
//   abf[n] = bf16(h@W1[0:64]); bsf[n] = bf16(h@W1[64:128]+b1)
//   acc[n] = sum_{e:dst=n} relu(abf[src] + bsf[n] + e*w128)   (wave/node, lane=feat)
//   out[n] = acc[n] @ W2 + cnt[n]*b2                          (fused readlane matvec)
// R9 = recovery: best measured components reassembled.
//   precompute: R5/R7 proven form (LDS dbuf h-tiles + volatile-pinned wreg[128] +
//     full-row ds_read batch). R8's "direct global loads" variant hit the
//     allocator's 128-VGPR wall -> h4 spilled (1.09GB scratch fetch, 621us).
//     Lesson: the allocator's behavior is part of the measured artifact; don't
//     restructure a proven kernel's memory path.
//   node_accum: R3 proven form (88.5us x3; epilogue alternatives all lost).
//   pipeline: R8's simplification kept (count+rank -> single-cursor alloc ->
//     non-atomic fill; shard machinery deleted, correctness-proven in R8).

#define PRE_NPB 128   // precompute: nodes per block (2 tiles of 64)

typedef unsigned int u32;

__device__ __forceinline__ void gload_lds16(const float* g, float* l) {
    __builtin_amdgcn_global_load_lds(
        (const __attribute__((address_space(1))) u32*)g,
        (__attribute__((address_space(3))) u32*)l,
        16, 0, 0);
}

// ---------------- count + rank ----------------
__global__ void count_kernel(const int* __restrict__ dst, int* __restrict__ counts,
                             int* __restrict__ rank, int n_edges) {
    int i = blockIdx.x * blockDim.x + threadIdx.x;
    if (i < n_edges) rank[i] = atomicAdd(&counts[dst[i]], 1);
}

// ---------------- offset allocation, single global cursor ----------------
__global__ __launch_bounds__(256) void alloc_offs_kernel(const int* __restrict__ counts,
                                                         int* __restrict__ gcursor,
                                                         int* __restrict__ offs, int n) {
    __shared__ int wsum[4];
    const int i    = blockIdx.x * 256 + threadIdx.x;
    const int lane = threadIdx.x & 63;
    const int wv   = threadIdx.x >> 6;

    const int c = (i < n) ? counts[i] : 0;
    int incl = c;
    #pragma unroll
    for (int d = 1; d < 64; d <<= 1) {
        int v = __shfl_up(incl, d, 64);
        if (lane >= d) incl += v;
    }
    const int excl = incl - c;
    if (lane == 63) wsum[wv] = incl;
    __syncthreads();
    if (threadIdx.x == 0) {
        const int s0 = wsum[0], s1 = wsum[1], s2 = wsum[2], s3 = wsum[3];
        const int b = atomicAdd(gcursor, s0 + s1 + s2 + s3);
        wsum[0] = b; wsum[1] = b + s0; wsum[2] = b + s0 + s1; wsum[3] = b + s0 + s1 + s2;
    }
    __syncthreads();
    if (i < n) offs[i] = wsum[wv] + excl;
}

// ---------------- single-pass non-atomic fill ----------------
__global__ void fill_kernel(const int* __restrict__ dst, const int* __restrict__ src,
                            const float* __restrict__ e,
                            const int* __restrict__ offs, const int* __restrict__ rank,
                            int2* __restrict__ meta, int n_edges) {
    const int i = blockIdx.x * blockDim.x + threadIdx.x;
    if (i >= n_edges) return;
    const int d = dst[i];
    meta[offs[d] + rank[i]] = make_int2(src[i], __float_as_int(e[i]));
}

// ---------------- abf = bf16(h@W1t), bsf = bf16(h@W1b + b1) ----------------
// lane = output feature j; wreg[k] = W1[k][j] pinned in 128 VGPRs; h tiles via LDS.
// (R5/R7 proven form, byte-for-byte)
__global__ __launch_bounds__(256, 2) void precompute_ab_kernel(
    const float* __restrict__ h, const float* __restrict__ W1, const float* __restrict__ b1,
    unsigned short* __restrict__ abf, unsigned short* __restrict__ bsf, int n_nodes)
{
    __shared__ float hbuf[2][64 * 64];             // 2 x 16KB tiles (64 nodes each)
    const int lane = threadIdx.x & 63;
    const int wv   = threadIdx.x >> 6;

    const int base = blockIdx.x * PRE_NPB;
    if (base >= n_nodes) return;
    const int nrem   = n_nodes - base;
    const int ntiles = (nrem >= PRE_NPB) ? (PRE_NPB / 64) : ((nrem + 63) >> 6);

    // one-time per-block: whole W1 column for this lane into VGPRs (L2-hot).
    // volatile asm pin: non-sinkable -> allocator can't push loads into the loop.
    float wreg[128];
    #pragma unroll
    for (int k = 0; k < 128; ++k) wreg[k] = W1[(size_t)k * 64 + lane];
    #pragma unroll
    for (int k = 0; k < 128; ++k) asm volatile("" : "+v"(wreg[k]));
    const float b1l = b1[lane];

    // stage tile t (64 nodes = 16KB) into hbuf[buf]
    auto stage = [&](int buf, int node_base) {
        if (node_base + 64 <= n_nodes) {
            // fast path: 16 x 1KB global_load_lds, 4 per wave, linear dest
            const float* gsrc = h + (size_t)node_base * 64;
            #pragma unroll
            for (int q = 0; q < 4; ++q) {
                const int c = wv * 4 + q;          // 1KB chunk id
                gload_lds16(gsrc + c * 256 + lane * 4, &hbuf[buf][c * 256]);
            }
        } else {
            // guarded tail: reg-staged float4 with bounds check
            #pragma unroll
            for (int q = 0; q < 4; ++q) {
                const int f4 = threadIdx.x + 256 * q;            // float4 idx in tile
                const long gf = (long)node_base * 16 + f4;       // global float4 idx
                float4 v = make_float4(0.f, 0.f, 0.f, 0.f);
                if (gf < (long)n_nodes * 16)
                    v = reinterpret_cast<const float4*>(h)[gf];
                reinterpret_cast<float4*>(hbuf[buf])[f4] = v;
            }
        }
    };

    // consume tile: wave wv handles nodes [wv*16, wv*16+16) of the tile.
    // per node: issue ALL 16 ds_read_b128 (full h row -> 64 VGPRs), then 128 fma.
    auto consume = [&](int buf, int node_base) {
        for (int i = 0; i < 16; ++i) {
            const int ln = wv * 16 + i;            // node-in-tile, wave-uniform
            const int n  = node_base + ln;
            if (n < n_nodes) {
                const float4* hr = reinterpret_cast<const float4*>(&hbuf[buf][ln * 64]);
                float4 h4[16];
                #pragma unroll
                for (int k4 = 0; k4 < 16; ++k4) h4[k4] = hr[k4];   // 16x ds_read_b128
                float av = 0.f, bv = b1l;
                #pragma unroll
                for (int k4 = 0; k4 < 16; ++k4) {    // same fma order as R3 (bitwise id.)
                    av = fmaf(h4[k4].x, wreg[4 * k4 + 0], av);
                    bv = fmaf(h4[k4].x, wreg[64 + 4 * k4 + 0], bv);
                    av = fmaf(h4[k4].y, wreg[4 * k4 + 1], av);
                    bv = fmaf(h4[k4].y, wreg[64 + 4 * k4 + 1], bv);
                    av = fmaf(h4[k4].z, wreg[4 * k4 + 2], av);
                    bv = fmaf(h4[k4].z, wreg[64 + 4 * k4 + 2], bv);
                    av = fmaf(h4[k4].w, wreg[4 * k4 + 3], av);
                    bv = fmaf(h4[k4].w, wreg[64 + 4 * k4 + 3], bv);
                }
                __hip_bfloat16 ab = __float2bfloat16(av);
                __hip_bfloat16 bb = __float2bfloat16(bv);
                abf[(size_t)n * 64 + lane] = *reinterpret_cast<unsigned short*>(&ab);
                bsf[(size_t)n * 64 + lane] = *reinterpret_cast<unsigned short*>(&bb);
            }
        }
    };

    stage(0, base);
    __syncthreads();                               // tile0 resident
    for (int t = 0; t < ntiles; ++t) {
        if (t + 1 < ntiles) stage((t + 1) & 1, base + (t + 1) * 64);  // prefetch next
        consume(t & 1, base + t * 64);             // compute current (covers latency)
        __syncthreads();                           // next tile resident / buffer free
    }
}

// ---------------- accum: wave/node, lane=feat, register-meta + depth-8 prefetch ----------------
// (R3 exactly — proven 88.5us x3)
__global__ __launch_bounds__(256) void node_accum_kernel(
    const unsigned short* __restrict__ abf, const unsigned short* __restrict__ bsf,
    const float* __restrict__ W1, const float* __restrict__ W2, const float* __restrict__ b2,
    const int* __restrict__ offs, const int* __restrict__ counts,
    const int2* __restrict__ meta, float* __restrict__ out, int n_nodes)
{
    const int lane = threadIdx.x & 63;
    const int wv   = __builtin_amdgcn_readfirstlane(threadIdx.x >> 6);
    const int n    = blockIdx.x * 4 + wv;          // wave-uniform node id
    if (n >= n_nodes) return;

    const float basel = __uint_as_float((uint)bsf[(size_t)n * 64 + lane] << 16);
    const float w128l = W1[(size_t)128 * 64 + lane];
    float acc = 0.f;

    const int beg = offs[n];     // s_load (n uniform)
    const int np  = counts[n];   // s_load

    // chunks of <=64 edges: meta staged into registers by ONE lane-parallel load,
    // per-edge src/e extracted with v_readlane (no memory on the gather-addr path)
    for (int c0 = 0; c0 < np; c0 += 64) {
        const int cn = min(np - c0, 64);

        int mx = 0, my = 0;
        if (lane < cn) {
            const int2 m = meta[beg + c0 + lane];   // 512B coalesced, once per chunk
            mx = m.x; my = m.y;
        }

        // pipeline slots hold the RAW zext ushort; <<16 happens at consume time
        uint x0=0,x1=0,x2=0,x3=0,x4=0,x5=0,x6=0,x7=0;

        auto ld = [&](int j, uint& x) {
            const int s = __builtin_amdgcn_readlane(mx, j);        // uniform src id
            x = (uint)abf[(size_t)s * 64 + lane];                  // saddr gather, 128B/wave
        };
        auto step = [&](int j, uint xr) {
            const float ev = __uint_as_float((uint)__builtin_amdgcn_readlane(my, j));
            const float xv = __uint_as_float(xr << 16);
            acc += fmaxf(fmaf(ev, w128l, basel) + xv, 0.f);
        };

        if (cn > 0) ld(0, x0);
        if (cn > 1) ld(1, x1);
        if (cn > 2) ld(2, x2);
        if (cn > 3) ld(3, x3);
        if (cn > 4) ld(4, x4);
        if (cn > 5) ld(5, x5);
        if (cn > 6) ld(6, x6);
        if (cn > 7) ld(7, x7);

        int i = 0;
        while (i + 16 <= cn) {
            step(i + 0, x0); ld(i + 8,  x0);
            step(i + 1, x1); ld(i + 9,  x1);
            step(i + 2, x2); ld(i + 10, x2);
            step(i + 3, x3); ld(i + 11, x3);
            step(i + 4, x4); ld(i + 12, x4);
            step(i + 5, x5); ld(i + 13, x5);
            step(i + 6, x6); ld(i + 14, x6);
            step(i + 7, x7); ld(i + 15, x7);
            i += 8;
        }
        const int r = cn - i;   // 0..15
        if (r > 0)  { step(i + 0, x0); }  if (r > 8)  { ld(i + 8,  x0); }
        if (r > 1)  { step(i + 1, x1); }  if (r > 9)  { ld(i + 9,  x1); }
        if (r > 2)  { step(i + 2, x2); }  if (r > 10) { ld(i + 10, x2); }
        if (r > 3)  { step(i + 3, x3); }  if (r > 11) { ld(i + 11, x3); }
        if (r > 4)  { step(i + 4, x4); }  if (r > 12) { ld(i + 12, x4); }
        if (r > 5)  { step(i + 5, x5); }  if (r > 13) { ld(i + 13, x5); }
        if (r > 6)  { step(i + 6, x6); }  if (r > 14) { ld(i + 14, x6); }
        if (r > 7)  { step(i + 7, x7); }
        if (r > 8)  { step(i + 8,  x0); }
        if (r > 9)  { step(i + 9,  x1); }
        if (r > 10) { step(i + 10, x2); }
        if (r > 11) { step(i + 11, x3); }
        if (r > 12) { step(i + 12, x4); }
        if (r > 13) { step(i + 13, x5); }
        if (r > 14) { step(i + 14, x6); }
    }

    // fused epilogue: out[n][lane] = sum_j acc_j * W2[j][lane] + np*b2[lane]
    float o = (float)np * b2[lane];
    #pragma unroll
    for (int j = 0; j < 64; ++j) {
        const float aj = __shfl(acc, j, 64);               // v_readlane
        o = fmaf(aj, W2[(size_t)j * 64 + lane], o);        // coalesced, L1-hot
    }
    out[(size_t)n * 64 + lane] = o;
}

extern "C" void kernel_launch(void* const* d_in, const int* in_sizes, int n_in,
                              void* d_out, int out_size, void* d_ws, size_t ws_size,
                              hipStream_t stream) {
    const float* h  = (const float*)d_in[0];
    const float* e  = (const float*)d_in[1];
    const int* src  = (const int*)d_in[2];
    const int* dst  = (const int*)d_in[3];
    const float* W1 = (const float*)d_in[4];
    const float* b1 = (const float*)d_in[5];
    const float* W2 = (const float*)d_in[6];
    const float* b2 = (const float*)d_in[7];
    float* out = (float*)d_out;

    const int n_edges = in_sizes[2];
    const int N = in_sizes[0] / 64;

    // ws: [counts N | gcursor 8 (1 used) | offs N | rank E] ints,
    //     [meta 2E] ints, [abf 64N ushort], [bsf 64N ushort]
    int* counts  = (int*)d_ws;
    int* gcursor = counts + N;
    int* offs    = gcursor + 8;
    int* rank    = offs + N;
    int2* meta   = (int2*)(rank + n_edges);
    unsigned short* abf = (unsigned short*)(meta + n_edges);
    unsigned short* bsf = abf + (size_t)64 * N;

    // zero counts + cursor every call
    hipMemsetAsync(counts, 0, ((size_t)N + 8) * sizeof(int), stream);

    const int eb = (n_edges + 255) / 256;
    const int nb = (N + 255) / 256;
    const int pg = (N + PRE_NPB - 1) / PRE_NPB;

    precompute_ab_kernel<<<pg, 256, 0, stream>>>(h, W1, b1, abf, bsf, N);
    count_kernel<<<eb, 256, 0, stream>>>(dst, counts, rank, n_edges);
    alloc_offs_kernel<<<nb, 256, 0, stream>>>(counts, gcursor, offs, N);
    fill_kernel<<<eb, 256, 0, stream>>>(dst, src, e, offs, rank, meta, n_edges);
    node_accum_kernel<<<(N + 3) / 4, 256, 0, stream>>>(abf, bsf, W1, W2, b2,
                                                       offs, counts, meta, out, N);
}

// Round 10
// 201.995 us; speedup vs baseline: 3.5443x; 1.1009x over previous
//
#include <hip/hip_runtime.h>
#include <hip/hip_bf16.h>

// EdgeConv, CSR-by-dst, bf16 intermediates:
//   abf[n] = bf16(h@W1[0:64]); bsf[n] = bf16(h@W1[64:128]+b1)
//   acc[n] = sum_{e:dst=n} relu(abf[src] + bsf[n] + e*w128)   (wave/node, lane=feat)
//   out[n] = acc[n] @ W2 + cnt[n]*b2                          (fused readlane matvec)
// R10: count fused INTO the precompute dispatch as a block role (blocks >= pg do
//   count+rank). The stream serializes the independent chains {count->alloc->fill}
//   and {precompute}; role-split runs count's ~25us of atomic latency UNDER
//   precompute's VALU/LDS execution for free (one stream, no events allowed).
//   Also removes one launch gap. Precompute body untouched (R5/R7/R9 proven:
//   LDS dbuf h-tiles + volatile-pinned wreg[128] + full-row ds_read batch).
// node_accum: R3 proven form (88.2-88.5us x4; epilogue alternatives all lost:
//   VGPR hoist sunk by regalloc (R4/R6), LDS ds_read_b32 slower than L1 (R7)).
// pipeline: count+rank -> single-cursor alloc -> non-atomic fill (R8-proven).

#define PRE_NPB 128   // precompute: nodes per block (2 tiles of 64)

typedef unsigned int u32;

__device__ __forceinline__ void gload_lds16(const float* g, float* l) {
    __builtin_amdgcn_global_load_lds(
        (const __attribute__((address_space(1))) u32*)g,
        (__attribute__((address_space(3))) u32*)l,
        16, 0, 0);
}

// ---------------- offset allocation, single global cursor ----------------
__global__ __launch_bounds__(256) void alloc_offs_kernel(const int* __restrict__ counts,
                                                         int* __restrict__ gcursor,
                                                         int* __restrict__ offs, int n) {
    __shared__ int wsum[4];
    const int i    = blockIdx.x * 256 + threadIdx.x;
    const int lane = threadIdx.x & 63;
    const int wv   = threadIdx.x >> 6;

    const int c = (i < n) ? counts[i] : 0;
    int incl = c;
    #pragma unroll
    for (int d = 1; d < 64; d <<= 1) {
        int v = __shfl_up(incl, d, 64);
        if (lane >= d) incl += v;
    }
    const int excl = incl - c;
    if (lane == 63) wsum[wv] = incl;
    __syncthreads();
    if (threadIdx.x == 0) {
        const int s0 = wsum[0], s1 = wsum[1], s2 = wsum[2], s3 = wsum[3];
        const int b = atomicAdd(gcursor, s0 + s1 + s2 + s3);
        wsum[0] = b; wsum[1] = b + s0; wsum[2] = b + s0 + s1; wsum[3] = b + s0 + s1 + s2;
    }
    __syncthreads();
    if (i < n) offs[i] = wsum[wv] + excl;
}

// ---------------- single-pass non-atomic fill ----------------
__global__ void fill_kernel(const int* __restrict__ dst, const int* __restrict__ src,
                            const float* __restrict__ e,
                            const int* __restrict__ offs, const int* __restrict__ rank,
                            int2* __restrict__ meta, int n_edges) {
    const int i = blockIdx.x * blockDim.x + threadIdx.x;
    if (i >= n_edges) return;
    const int d = dst[i];
    meta[offs[d] + rank[i]] = make_int2(src[i], __float_as_int(e[i]));
}

// ---------------- fused: precompute (blocks < pg) + count/rank (blocks >= pg) ----------------
// precompute: lane = output feature j; wreg[k] = W1[k][j] pinned in 128 VGPRs;
//             h tiles via LDS double-buffer (R5/R7/R9 proven form, body unchanged).
// count role: rank[i] = atomicAdd(&counts[dst[i]], 1) — hides under precompute.
__global__ __launch_bounds__(256, 2) void pre_count_kernel(
    const float* __restrict__ h, const float* __restrict__ W1, const float* __restrict__ b1,
    unsigned short* __restrict__ abf, unsigned short* __restrict__ bsf, int n_nodes,
    const int* __restrict__ dst, int* __restrict__ counts, int* __restrict__ rank,
    int n_edges, int pg)
{
    __shared__ float hbuf[2][64 * 64];             // 2 x 16KB tiles (64 nodes each)
    const int lane = threadIdx.x & 63;
    const int wv   = threadIdx.x >> 6;

    if ((int)blockIdx.x >= pg) {
        // ---- count role ----
        const int i = ((int)blockIdx.x - pg) * 256 + threadIdx.x;
        if (i < n_edges) rank[i] = atomicAdd(&counts[dst[i]], 1);
        return;
    }

    // ---- precompute role (byte-for-byte R9 body) ----
    const int base = blockIdx.x * PRE_NPB;
    if (base >= n_nodes) return;
    const int nrem   = n_nodes - base;
    const int ntiles = (nrem >= PRE_NPB) ? (PRE_NPB / 64) : ((nrem + 63) >> 6);

    // one-time per-block: whole W1 column for this lane into VGPRs (L2-hot).
    // volatile asm pin: non-sinkable -> allocator can't push loads into the loop.
    float wreg[128];
    #pragma unroll
    for (int k = 0; k < 128; ++k) wreg[k] = W1[(size_t)k * 64 + lane];
    #pragma unroll
    for (int k = 0; k < 128; ++k) asm volatile("" : "+v"(wreg[k]));
    const float b1l = b1[lane];

    // stage tile t (64 nodes = 16KB) into hbuf[buf]
    auto stage = [&](int buf, int node_base) {
        if (node_base + 64 <= n_nodes) {
            // fast path: 16 x 1KB global_load_lds, 4 per wave, linear dest
            const float* gsrc = h + (size_t)node_base * 64;
            #pragma unroll
            for (int q = 0; q < 4; ++q) {
                const int c = wv * 4 + q;          // 1KB chunk id
                gload_lds16(gsrc + c * 256 + lane * 4, &hbuf[buf][c * 256]);
            }
        } else {
            // guarded tail: reg-staged float4 with bounds check
            #pragma unroll
            for (int q = 0; q < 4; ++q) {
                const int f4 = threadIdx.x + 256 * q;            // float4 idx in tile
                const long gf = (long)node_base * 16 + f4;       // global float4 idx
                float4 v = make_float4(0.f, 0.f, 0.f, 0.f);
                if (gf < (long)n_nodes * 16)
                    v = reinterpret_cast<const float4*>(h)[gf];
                reinterpret_cast<float4*>(hbuf[buf])[f4] = v;
            }
        }
    };

    // consume tile: wave wv handles nodes [wv*16, wv*16+16) of the tile.
    // per node: issue ALL 16 ds_read_b128 (full h row -> 64 VGPRs), then 128 fma.
    auto consume = [&](int buf, int node_base) {
        for (int i = 0; i < 16; ++i) {
            const int ln = wv * 16 + i;            // node-in-tile, wave-uniform
            const int n  = node_base + ln;
            if (n < n_nodes) {
                const float4* hr = reinterpret_cast<const float4*>(&hbuf[buf][ln * 64]);
                float4 h4[16];
                #pragma unroll
                for (int k4 = 0; k4 < 16; ++k4) h4[k4] = hr[k4];   // 16x ds_read_b128
                float av = 0.f, bv = b1l;
                #pragma unroll
                for (int k4 = 0; k4 < 16; ++k4) {    // same fma order as R3 (bitwise id.)
                    av = fmaf(h4[k4].x, wreg[4 * k4 + 0], av);
                    bv = fmaf(h4[k4].x, wreg[64 + 4 * k4 + 0], bv);
                    av = fmaf(h4[k4].y, wreg[4 * k4 + 1], av);
                    bv = fmaf(h4[k4].y, wreg[64 + 4 * k4 + 1], bv);
                    av = fmaf(h4[k4].z, wreg[4 * k4 + 2], av);
                    bv = fmaf(h4[k4].z, wreg[64 + 4 * k4 + 2], bv);
                    av = fmaf(h4[k4].w, wreg[4 * k4 + 3], av);
                    bv = fmaf(h4[k4].w, wreg[64 + 4 * k4 + 3], bv);
                }
                __hip_bfloat16 ab = __float2bfloat16(av);
                __hip_bfloat16 bb = __float2bfloat16(bv);
                abf[(size_t)n * 64 + lane] = *reinterpret_cast<unsigned short*>(&ab);
                bsf[(size_t)n * 64 + lane] = *reinterpret_cast<unsigned short*>(&bb);
            }
        }
    };

    stage(0, base);
    __syncthreads();                               // tile0 resident
    for (int t = 0; t < ntiles; ++t) {
        if (t + 1 < ntiles) stage((t + 1) & 1, base + (t + 1) * 64);  // prefetch next
        consume(t & 1, base + t * 64);             // compute current (covers latency)
        __syncthreads();                           // next tile resident / buffer free
    }
}

// ---------------- accum: wave/node, lane=feat, register-meta + depth-8 prefetch ----------------
// (R3 exactly — proven 88.2-88.5us x4)
__global__ __launch_bounds__(256) void node_accum_kernel(
    const unsigned short* __restrict__ abf, const unsigned short* __restrict__ bsf,
    const float* __restrict__ W1, const float* __restrict__ W2, const float* __restrict__ b2,
    const int* __restrict__ offs, const int* __restrict__ counts,
    const int2* __restrict__ meta, float* __restrict__ out, int n_nodes)
{
    const int lane = threadIdx.x & 63;
    const int wv   = __builtin_amdgcn_readfirstlane(threadIdx.x >> 6);
    const int n    = blockIdx.x * 4 + wv;          // wave-uniform node id
    if (n >= n_nodes) return;

    const float basel = __uint_as_float((uint)bsf[(size_t)n * 64 + lane] << 16);
    const float w128l = W1[(size_t)128 * 64 + lane];
    float acc = 0.f;

    const int beg = offs[n];     // s_load (n uniform)
    const int np  = counts[n];   // s_load

    // chunks of <=64 edges: meta staged into registers by ONE lane-parallel load,
    // per-edge src/e extracted with v_readlane (no memory on the gather-addr path)
    for (int c0 = 0; c0 < np; c0 += 64) {
        const int cn = min(np - c0, 64);

        int mx = 0, my = 0;
        if (lane < cn) {
            const int2 m = meta[beg + c0 + lane];   // 512B coalesced, once per chunk
            mx = m.x; my = m.y;
        }

        // pipeline slots hold the RAW zext ushort; <<16 happens at consume time
        uint x0=0,x1=0,x2=0,x3=0,x4=0,x5=0,x6=0,x7=0;

        auto ld = [&](int j, uint& x) {
            const int s = __builtin_amdgcn_readlane(mx, j);        // uniform src id
            x = (uint)abf[(size_t)s * 64 + lane];                  // saddr gather, 128B/wave
        };
        auto step = [&](int j, uint xr) {
            const float ev = __uint_as_float((uint)__builtin_amdgcn_readlane(my, j));
            const float xv = __uint_as_float(xr << 16);
            acc += fmaxf(fmaf(ev, w128l, basel) + xv, 0.f);
        };

        if (cn > 0) ld(0, x0);
        if (cn > 1) ld(1, x1);
        if (cn > 2) ld(2, x2);
        if (cn > 3) ld(3, x3);
        if (cn > 4) ld(4, x4);
        if (cn > 5) ld(5, x5);
        if (cn > 6) ld(6, x6);
        if (cn > 7) ld(7, x7);

        int i = 0;
        while (i + 16 <= cn) {
            step(i + 0, x0); ld(i + 8,  x0);
            step(i + 1, x1); ld(i + 9,  x1);
            step(i + 2, x2); ld(i + 10, x2);
            step(i + 3, x3); ld(i + 11, x3);
            step(i + 4, x4); ld(i + 12, x4);
            step(i + 5, x5); ld(i + 13, x5);
            step(i + 6, x6); ld(i + 14, x6);
            step(i + 7, x7); ld(i + 15, x7);
            i += 8;
        }
        const int r = cn - i;   // 0..15
        if (r > 0)  { step(i + 0, x0); }  if (r > 8)  { ld(i + 8,  x0); }
        if (r > 1)  { step(i + 1, x1); }  if (r > 9)  { ld(i + 9,  x1); }
        if (r > 2)  { step(i + 2, x2); }  if (r > 10) { ld(i + 10, x2); }
        if (r > 3)  { step(i + 3, x3); }  if (r > 11) { ld(i + 11, x3); }
        if (r > 4)  { step(i + 4, x4); }  if (r > 12) { ld(i + 12, x4); }
        if (r > 5)  { step(i + 5, x5); }  if (r > 13) { ld(i + 13, x5); }
        if (r > 6)  { step(i + 6, x6); }  if (r > 14) { ld(i + 14, x6); }
        if (r > 7)  { step(i + 7, x7); }
        if (r > 8)  { step(i + 8,  x0); }
        if (r > 9)  { step(i + 9,  x1); }
        if (r > 10) { step(i + 10, x2); }
        if (r > 11) { step(i + 11, x3); }
        if (r > 12) { step(i + 12, x4); }
        if (r > 13) { step(i + 13, x5); }
        if (r > 14) { step(i + 14, x6); }
    }

    // fused epilogue: out[n][lane] = sum_j acc_j * W2[j][lane] + np*b2[lane]
    float o = (float)np * b2[lane];
    #pragma unroll
    for (int j = 0; j < 64; ++j) {
        const float aj = __shfl(acc, j, 64);               // v_readlane
        o = fmaf(aj, W2[(size_t)j * 64 + lane], o);        // coalesced, L1-hot
    }
    out[(size_t)n * 64 + lane] = o;
}

extern "C" void kernel_launch(void* const* d_in, const int* in_sizes, int n_in,
                              void* d_out, int out_size, void* d_ws, size_t ws_size,
                              hipStream_t stream) {
    const float* h  = (const float*)d_in[0];
    const float* e  = (const float*)d_in[1];
    const int* src  = (const int*)d_in[2];
    const int* dst  = (const int*)d_in[3];
    const float* W1 = (const float*)d_in[4];
    const float* b1 = (const float*)d_in[5];
    const float* W2 = (const float*)d_in[6];
    const float* b2 = (const float*)d_in[7];
    float* out = (float*)d_out;

    const int n_edges = in_sizes[2];
    const int N = in_sizes[0] / 64;

    // ws: [counts N | gcursor 8 (1 used) | offs N | rank E] ints,
    //     [meta 2E] ints, [abf 64N ushort], [bsf 64N ushort]
    int* counts  = (int*)d_ws;
    int* gcursor = counts + N;
    int* offs    = gcursor + 8;
    int* rank    = offs + N;
    int2* meta   = (int2*)(rank + n_edges);
    unsigned short* abf = (unsigned short*)(meta + n_edges);
    unsigned short* bsf = abf + (size_t)64 * N;

    // zero counts + cursor every call
    hipMemsetAsync(counts, 0, ((size_t)N + 8) * sizeof(int), stream);

    const int eb = (n_edges + 255) / 256;
    const int nb = (N + 255) / 256;
    const int pg = (N + PRE_NPB - 1) / PRE_NPB;

    pre_count_kernel<<<pg + eb, 256, 0, stream>>>(h, W1, b1, abf, bsf, N,
                                                  dst, counts, rank, n_edges, pg);
    alloc_offs_kernel<<<nb, 256, 0, stream>>>(counts, gcursor, offs, N);
    fill_kernel<<<eb, 256, 0, stream>>>(dst, src, e, offs, rank, meta, n_edges);
    node_accum_kernel<<<(N + 3) / 4, 256, 0, stream>>>(abf, bsf, W1, W2, b2,
                                                       offs, counts, meta, out, N);
}